// Round 2
// baseline (5504.060 us; speedup 1.0000x reference)
//
#include <hip/hip_runtime.h>

typedef _Float16 f16;
typedef _Float16 h2 __attribute__((ext_vector_type(2)));
typedef _Float16 h4 __attribute__((ext_vector_type(4)));
typedef _Float16 h8 __attribute__((ext_vector_type(8)));

#define T127 127

__device__ __forceinline__ float rcp_f(float x) { return __builtin_amdgcn_rcpf(x); }

__device__ __forceinline__ float fdot2(h2 a, h2 b, float c) {
  return __builtin_amdgcn_fdot2(a, b, c, false);
}
__device__ __forceinline__ h2 mk2(f16 a, f16 b) { h2 v; v[0] = a; v[1] = b; return v; }

__device__ __forceinline__ float fast_tanh(float x) {
  x = fminf(fmaxf(x, -12.f), 12.f);
  float e = __expf(2.f * x);
  return (e - 1.f) * rcp_f(e + 1.f);
}
__device__ __forceinline__ float fast_sig(float x) {
  x = fminf(fmaxf(x, -30.f), 30.f);
  return rcp_f(1.f + __expf(-x));
}

// Pack Whh fp32 [1024][256] -> fp16 d_ws layout [32][1024][8]:
// ws[(c*1024 + r)*8 + j] = Whh[r][8c + j]  (lane-coalesced stream reads)
__global__ void pack_whh(const float* __restrict__ Whh, f16* __restrict__ ws) {
  int r = blockIdx.x;     // 0..1023
  int col = threadIdx.x;  // 0..255
  float v = Whh[r * 256 + col];
  int c = col >> 3, j = col & 7;
  ws[((size_t)(c * 1024 + r)) * 8 + j] = (f16)v;
}

// One block per 2 batches; 256 blocks x 1024 threads (16 waves/CU, <=128 VGPR).
// Wa1-hc fp16 in regs (64/lane, zero-dup); Whh streamed fp16 from L2 (d_ws);
// tE1 = tanh(e.W1e) fp16 resident in LDS for all 127 steps.
__global__ __launch_bounds__(1024, 4) void decoder_kernel(
    const float* __restrict__ enc,    // [512][127][256]
    const float* __restrict__ yhist,  // [512][127]
    const float* __restrict__ Wa1,    // [256][768]  cols: h(0:256) c(256:512) e(512:768)
    const float* __restrict__ ba1,    // [256]
    const float* __restrict__ Wa2,    // [256]
    const float* __restrict__ ba2,    // [1]
    const float* __restrict__ Wih,    // [1024]
    const float* __restrict__ Whh,    // [1024][256] (unused in loop; packed copy in wsW)
    const float* __restrict__ bih,    // [1024]
    const float* __restrict__ bhh,    // [1024]
    const float* __restrict__ Wfc,    // [257]
    const float* __restrict__ bfc,    // [1]
    const float* __restrict__ Wfcf,   // [512]
    const float* __restrict__ bfcf,   // [1]
    const f16* __restrict__ wsW,      // [32][1024][8] packed Whh fp16
    float* __restrict__ outp)         // [512] out ++ [512][127][127] weight
{
  __shared__ __align__(16) f16 tE1[2][T127][260];   // tanh(E1) fp16, padded rows
  __shared__ __align__(16) f16 hch[2][4][136];      // [h;c] fp16, 4 chunks of 128 (+8 pad)
  __shared__ __align__(16) float s_arr[2][4][68];   // s = tanh(u+b1), 4 chunks of 64 (+4 pad)
  __shared__ __align__(16) float score_s[2][128];
  __shared__ __align__(16) float p_s[2][128];       // e . Wfc[0:256]
  __shared__ __align__(16) float q_s[2][128];       // e . Wfcf[256:512]
  __shared__ __align__(16) char ovl[8192];          // est [16][256] f16  UNION  gact [2][1024] f32
  __shared__ __align__(16) float c_s[2][256];       // exact fp32 cell state
  __shared__ __align__(16) float w2_lds[256];
  __shared__ float ytil[2], ctxq_s[2], red[16];

  float* gact = (float*)ovl;
  f16* est = (f16*)ovl;

  const int L = threadIdx.x;
  const int b0 = blockIdx.x * 2;
  const int k_u = L >> 2;  // output index 0..255 (u / score-pair)
  const int g_u = L & 3;   // quad member: col-chunk selector

  // ---------------- init ----------------
  for (int i = L; i < 1088; i += 1024) ((f16*)hch)[i] = (f16)0.f;
  if (L < 512) ((float*)c_s)[L] = 0.f;
  if (L < 256) w2_lds[L] = Wa2[L];

  // ---------------- prologue: tE1 = tanh(e.W1e), p, q ----------------
  {
    // quad-split W1e: lane holds 64 cols (32 h2 regs)
    h2 we1[32];
    {
      const float4* wrow = (const float4*)(Wa1 + (size_t)k_u * 768 + 512 + g_u * 64);
#pragma unroll
      for (int i = 0; i < 16; ++i) {
        float4 w = wrow[i];
        we1[2 * i]     = mk2((f16)w.x, (f16)w.y);
        we1[2 * i + 1] = mk2((f16)w.z, (f16)w.w);
      }
    }
    const int prpair = L >> 6;  // wave id = staging pair 0..15
    const int lm = L & 63;

#pragma unroll 1
    for (int tt = 0; tt < 16; ++tt) {
      __syncthreads();
      {  // stage 16 (b,j) rows of e as fp16: pair = bb*8 + j8, j = tt*8+j8
        int bbs = prpair >> 3, j8 = prpair & 7, j = tt * 8 + j8;
        float4 v = make_float4(0.f, 0.f, 0.f, 0.f);
        if (j < T127)
          v = *(const float4*)(enc + (((size_t)(b0 + bbs)) * T127 + j) * 256 + lm * 4);
        h4 hv; hv[0] = (f16)v.x; hv[1] = (f16)v.y; hv[2] = (f16)v.z; hv[3] = (f16)v.w;
        *(h4*)(est + prpair * 256 + lm * 4) = hv;
      }
      __syncthreads();
      // every quad computes all 16 pairs: 64-col partial dot + quad reduce
#pragma unroll 1
      for (int P = 0; P < 16; ++P) {
        int bbs = P >> 3, j8 = P & 7, j = tt * 8 + j8;
        const h8* ep = (const h8*)(est + P * 256 + g_u * 64);
        float a0 = 0.f, a1 = 0.f;
#pragma unroll
        for (int r = 0; r < 8; ++r) {
          h8 e8 = ep[r];
          a0 = fdot2(we1[4 * r + 0], mk2(e8[0], e8[1]), a0);
          a1 = fdot2(we1[4 * r + 1], mk2(e8[2], e8[3]), a1);
          a0 = fdot2(we1[4 * r + 2], mk2(e8[4], e8[5]), a0);
          a1 = fdot2(we1[4 * r + 3], mk2(e8[6], e8[7]), a1);
        }
        float acc = a0 + a1;
        acc += __shfl_xor(acc, 1, 64);
        acc += __shfl_xor(acc, 2, 64);
        if (g_u == 0 && j < T127) tE1[bbs][j][k_u] = (f16)fast_tanh(acc);
      }
      {  // p, q for this wave's pair
        int P = prpair, bbs = P >> 3, j8 = P & 7, j = tt * 8 + j8;
        float4 wp4 = *(const float4*)(Wfc + lm * 4);
        float4 wq4 = *(const float4*)(Wfcf + 256 + lm * 4);
        h4 ev = *(const h4*)(est + P * 256 + lm * 4);
        float pacc = (float)ev[0] * wp4.x + (float)ev[1] * wp4.y + (float)ev[2] * wp4.z + (float)ev[3] * wp4.w;
        float qacc = (float)ev[0] * wq4.x + (float)ev[1] * wq4.y + (float)ev[2] * wq4.z + (float)ev[3] * wq4.w;
#pragma unroll
        for (int s = 32; s; s >>= 1) {
          pacc += __shfl_xor(pacc, s, 64);
          qacc += __shfl_xor(qacc, s, 64);
        }
        if (lm == 0 && j < T127) { p_s[bbs][j] = pacc; q_s[bbs][j] = qacc; }
      }
    }
  }
  __syncthreads();

  // ---------------- persistent registers ----------------
  h2 w1[64];  // Wa1[k_u, g_u*128 : +128] (h|c part), fp16
  {
    const float4* wrow = (const float4*)(Wa1 + (size_t)k_u * 768 + g_u * 128);
#pragma unroll
    for (int i = 0; i < 32; ++i) {
      float4 w = wrow[i];
      w1[2 * i]     = mk2((f16)w.x, (f16)w.y);
      w1[2 * i + 1] = mk2((f16)w.z, (f16)w.w);
    }
  }
  const float b1k = ba1[k_u];
  const float wihn = Wih[L];
  const float biasn = bih[L] + bhh[L];
  const float ba2v = ba2[0];
  const float wfcy = Wfc[256];
  const float bfc0 = bfc[0];
  __syncthreads();

  // ---------------- 127 sequential steps ----------------
#pragma unroll 1
  for (int t = 0; t < T127; ++t) {
    // prefetch first Whh stream chunks (land during u-dots)
    const h8* wp = (const h8*)wsW + L;  // chunk c at wp[c*1024]
    h8 wv0 = wp[0];
    h8 wv1 = wp[1024];

    // ---- Phase A1: u = W1.[h;c] -> s=tanh(u+b1)  (register weights) ----
    float u0a = 0.f, u0b = 0.f, u1a = 0.f, u1b = 0.f;
    {
      const h8* hp = (const h8*)&hch[0][g_u][0];
#pragma unroll
      for (int r = 0; r < 16; ++r) {
        h8 a = hp[r];
        u0a = fdot2(w1[4 * r + 0], mk2(a[0], a[1]), u0a);
        u0b = fdot2(w1[4 * r + 1], mk2(a[2], a[3]), u0b);
        u0a = fdot2(w1[4 * r + 2], mk2(a[4], a[5]), u0a);
        u0b = fdot2(w1[4 * r + 3], mk2(a[6], a[7]), u0b);
      }
      hp = (const h8*)&hch[1][g_u][0];
#pragma unroll
      for (int r = 0; r < 16; ++r) {
        h8 a = hp[r];
        u1a = fdot2(w1[4 * r + 0], mk2(a[0], a[1]), u1a);
        u1b = fdot2(w1[4 * r + 1], mk2(a[2], a[3]), u1b);
        u1a = fdot2(w1[4 * r + 2], mk2(a[4], a[5]), u1a);
        u1b = fdot2(w1[4 * r + 3], mk2(a[6], a[7]), u1b);
      }
    }

    // ---- Phase A2: gh = Whh.h, Whh streamed from L2, 2-deep pipeline ----
    float gh0 = 0.f, gh1 = 0.f;
#pragma unroll 1
    for (int cb = 0; cb < 16; ++cb) {
      int cn0 = (cb < 15) ? (cb * 2 + 2) : 0;  // wrap: harmless dummy load last iter
      int cn1 = (cb < 15) ? (cb * 2 + 3) : 1;
      h8 n0 = wp[cn0 * 1024];
      h8 n1 = wp[cn1 * 1024];
      int c0 = cb * 2, c1 = cb * 2 + 1;
      h8 h00 = *(const h8*)&hch[0][c0 >> 4][(c0 & 15) * 8];
      h8 h01 = *(const h8*)&hch[0][c1 >> 4][(c1 & 15) * 8];
      h8 h10 = *(const h8*)&hch[1][c0 >> 4][(c0 & 15) * 8];
      h8 h11 = *(const h8*)&hch[1][c1 >> 4][(c1 & 15) * 8];
      gh0 = fdot2(mk2(wv0[0], wv0[1]), mk2(h00[0], h00[1]), gh0);
      gh0 = fdot2(mk2(wv0[2], wv0[3]), mk2(h00[2], h00[3]), gh0);
      gh0 = fdot2(mk2(wv0[4], wv0[5]), mk2(h00[4], h00[5]), gh0);
      gh0 = fdot2(mk2(wv0[6], wv0[7]), mk2(h00[6], h00[7]), gh0);
      gh1 = fdot2(mk2(wv0[0], wv0[1]), mk2(h10[0], h10[1]), gh1);
      gh1 = fdot2(mk2(wv0[2], wv0[3]), mk2(h10[2], h10[3]), gh1);
      gh1 = fdot2(mk2(wv0[4], wv0[5]), mk2(h10[4], h10[5]), gh1);
      gh1 = fdot2(mk2(wv0[6], wv0[7]), mk2(h10[6], h10[7]), gh1);
      gh0 = fdot2(mk2(wv1[0], wv1[1]), mk2(h01[0], h01[1]), gh0);
      gh0 = fdot2(mk2(wv1[2], wv1[3]), mk2(h01[2], h01[3]), gh0);
      gh0 = fdot2(mk2(wv1[4], wv1[5]), mk2(h01[4], h01[5]), gh0);
      gh0 = fdot2(mk2(wv1[6], wv1[7]), mk2(h01[6], h01[7]), gh0);
      gh1 = fdot2(mk2(wv1[0], wv1[1]), mk2(h11[0], h11[1]), gh1);
      gh1 = fdot2(mk2(wv1[2], wv1[3]), mk2(h11[2], h11[3]), gh1);
      gh1 = fdot2(mk2(wv1[4], wv1[5]), mk2(h11[4], h11[5]), gh1);
      gh1 = fdot2(mk2(wv1[6], wv1[7]), mk2(h11[6], h11[7]), gh1);
      wv0 = n0; wv1 = n1;
    }

    // ---- u quad-reduce + s write ----
    float u0 = u0a + u0b, u1 = u1a + u1b;
    u0 += __shfl_xor(u0, 1, 64); u0 += __shfl_xor(u0, 2, 64);
    u1 += __shfl_xor(u1, 1, 64); u1 += __shfl_xor(u1, 2, 64);
    if (g_u == 0) s_arr[0][k_u >> 6][k_u & 63] = fast_tanh(u0 + b1k);
    else if (g_u == 1) s_arr[1][k_u >> 6][k_u & 63] = fast_tanh(u1 + b1k);
    __syncthreads();

    // ---- Phase B: scores via tanh(u+E) = (s+t)/(1+st) ----
    {
      const int pr = k_u;  // pair 0..255; valid < 254
      if (pr < 254) {
        const int bb = pr & 1;
        const int j = pr >> 1;
        const h4* tp = (const h4*)&tE1[bb][j][g_u * 64];
        const float4* sp = (const float4*)&s_arr[bb][g_u][0];
        const float4* w2p = (const float4*)&w2_lds[g_u * 64];
        float acc0 = 0.f, acc1 = 0.f;
#pragma unroll
        for (int i = 0; i < 16; ++i) {
          h4 tv = tp[i];
          float4 sv = sp[i];
          float4 wv = w2p[i];
          float t0 = (float)tv[0], t1 = (float)tv[1], t2 = (float)tv[2], t3 = (float)tv[3];
          acc0 = fmaf(wv.x * (sv.x + t0), rcp_f(fmaf(sv.x, t0, 1.f)), acc0);
          acc1 = fmaf(wv.y * (sv.y + t1), rcp_f(fmaf(sv.y, t1, 1.f)), acc1);
          acc0 = fmaf(wv.z * (sv.z + t2), rcp_f(fmaf(sv.z, t2, 1.f)), acc0);
          acc1 = fmaf(wv.w * (sv.w + t3), rcp_f(fmaf(sv.w, t3, 1.f)), acc1);
        }
        float acc = acc0 + acc1;
        acc += __shfl_xor(acc, 1, 64);
        acc += __shfl_xor(acc, 2, 64);
        if (g_u == 0) score_s[bb][j] = acc + ba2v;
      }
    }
    __syncthreads();

    // ---- Phase C: softmax, attn write, context dots, y_tilde ----
    {
      const int wv = L >> 6, ln = L & 63;
      if (wv < 2) {
        const int bb = wv;
        const int batch = b0 + bb;
        float x0 = score_s[bb][ln];
        float x1 = (ln < 63) ? score_s[bb][64 + ln] : -3.4e38f;
        float m = fmaxf(x0, x1);
#pragma unroll
        for (int s = 32; s; s >>= 1) m = fmaxf(m, __shfl_xor(m, s, 64));
        float e0 = __expf(x0 - m);
        float e1 = (ln < 63) ? __expf(x1 - m) : 0.f;
        float ssum = e0 + e1;
#pragma unroll
        for (int s = 32; s; s >>= 1) ssum += __shfl_xor(ssum, s, 64);
        float rs = rcp_f(ssum);
        float a0 = e0 * rs, a1 = e1 * rs;
        float* wout = outp + 512 + ((size_t)batch * T127 + t) * T127;
        wout[ln] = a0;
        if (ln < 63) wout[64 + ln] = a1;
        float cw = a0 * p_s[bb][ln] + ((ln < 63) ? a1 * p_s[bb][64 + ln] : 0.f);
#pragma unroll
        for (int s = 32; s; s >>= 1) cw += __shfl_xor(cw, s, 64);
        if (ln == 0) ytil[bb] = cw + wfcy * yhist[(size_t)batch * T127 + t] + bfc0;
        if (t == T127 - 1) {
          float cq = a0 * q_s[bb][ln] + ((ln < 63) ? a1 * q_s[bb][64 + ln] : 0.f);
#pragma unroll
          for (int s = 32; s; s >>= 1) cq += __shfl_xor(cq, s, 64);
          if (ln == 0) ctxq_s[bb] = cq;
        }
      }
    }
    __syncthreads();

    // ---- Phase D: gates + activations ----
    {
      float g0 = gh0 + wihn * ytil[0] + biasn;
      float g1 = gh1 + wihn * ytil[1] + biasn;
      bool is_g = (L >= 512) && (L < 768);
      float a0 = is_g ? fast_tanh(g0) : fast_sig(g0);
      float a1 = is_g ? fast_tanh(g1) : fast_sig(g1);
      gact[L] = a0;
      gact[1024 + L] = a1;
    }
    __syncthreads();

    // ---- Phase E: LSTM cell update ----
    if (L < 512) {
      const int bb = L >> 8, kk = L & 255;
      float gi = gact[bb * 1024 + kk];
      float gf = gact[bb * 1024 + 256 + kk];
      float gg = gact[bb * 1024 + 512 + kk];
      float go = gact[bb * 1024 + 768 + kk];
      float cn = gf * c_s[bb][kk] + gi * gg;
      float hn = go * fast_tanh(cn);
      c_s[bb][kk] = cn;
      hch[bb][kk >> 7][kk & 127] = (f16)hn;
      hch[bb][2 + (kk >> 7)][kk & 127] = (f16)cn;
      if (t == T127 - 1) {
        float po = Wfcf[kk] * hn;
#pragma unroll
        for (int s = 32; s; s >>= 1) po += __shfl_xor(po, s, 64);
        if ((L & 63) == 0) red[L >> 6] = po;
      }
    }
    __syncthreads();
  }

  // ---------------- final: out = Wfcf[0:256].h + ctx.Wfcf[256:512] + b ----------------
  if (L < 2) {
    float o = red[L * 4] + red[L * 4 + 1] + red[L * 4 + 2] + red[L * 4 + 3] + ctxq_s[L] + bfcf[0];
    outp[b0 + L] = o;
  }
}

extern "C" void kernel_launch(void* const* d_in, const int* in_sizes, int n_in,
                              void* d_out, int out_size, void* d_ws, size_t ws_size,
                              hipStream_t stream) {
  (void)in_sizes; (void)n_in; (void)out_size; (void)ws_size;
  f16* wsW = (f16*)d_ws;  // needs 32*1024*8*2 = 512 KiB
  pack_whh<<<1024, 256, 0, stream>>>((const float*)d_in[7], wsW);
  decoder_kernel<<<256, 1024, 0, stream>>>(
      (const float*)d_in[0], (const float*)d_in[1], (const float*)d_in[2],
      (const float*)d_in[3], (const float*)d_in[4], (const float*)d_in[5],
      (const float*)d_in[6], (const float*)d_in[7], (const float*)d_in[8],
      (const float*)d_in[9], (const float*)d_in[10], (const float*)d_in[11],
      (const float*)d_in[12], (const float*)d_in[13], wsW, (float*)d_out);
}

// Round 3
// 5185.847 us; speedup vs baseline: 1.0614x; 1.0614x over previous
//
#include <hip/hip_runtime.h>

typedef _Float16 f16;
typedef _Float16 h2 __attribute__((ext_vector_type(2)));
typedef _Float16 h4 __attribute__((ext_vector_type(4)));
typedef _Float16 h8 __attribute__((ext_vector_type(8)));

#define T127 127

__device__ __forceinline__ float rcp_f(float x) { return __builtin_amdgcn_rcpf(x); }

__device__ __forceinline__ float fdot2(h2 a, h2 b, float c) {
  return __builtin_amdgcn_fdot2(a, b, c, false);
}
__device__ __forceinline__ h2 mk2(f16 a, f16 b) { h2 v; v[0] = a; v[1] = b; return v; }

__device__ __forceinline__ float fast_tanh(float x) {
  x = fminf(fmaxf(x, -12.f), 12.f);
  float e = __expf(2.f * x);
  return (e - 1.f) * rcp_f(e + 1.f);
}
__device__ __forceinline__ float fast_sig(float x) {
  x = fminf(fmaxf(x, -30.f), 30.f);
  return rcp_f(1.f + __expf(-x));
}

// Pack Whh fp32 [1024][256] -> fp16 d_ws layout [32][1024][8]:
// ws[(c*1024 + r)*8 + j] = Whh[r][8c + j]  (lane-coalesced stream reads)
__global__ void pack_whh(const float* __restrict__ Whh, f16* __restrict__ ws) {
  int r = blockIdx.x;     // 0..1023
  int col = threadIdx.x;  // 0..255
  float v = Whh[r * 256 + col];
  int c = col >> 3, j = col & 7;
  ws[((size_t)(c * 1024 + r)) * 8 + j] = (f16)v;
}

// One block per 2 batches; 256 blocks x 1024 threads, 1 block/CU (LDS-bound).
// launch_bounds(1024,1): 16-wave workgroup -> VGPR cap 128 (NOT 64 — the
// (1024,4) variant was clamped to 64 VGPRs and spilled w1[] to scratch:
// 5.4 GB/launch of scratch traffic. Keep this at 1.)
__global__ __launch_bounds__(1024, 1) void decoder_kernel(
    const float* __restrict__ enc,    // [512][127][256]
    const float* __restrict__ yhist,  // [512][127]
    const float* __restrict__ Wa1,    // [256][768]  cols: h(0:256) c(256:512) e(512:768)
    const float* __restrict__ ba1,    // [256]
    const float* __restrict__ Wa2,    // [256]
    const float* __restrict__ ba2,    // [1]
    const float* __restrict__ Wih,    // [1024]
    const float* __restrict__ Whh,    // [1024][256] (unused in loop; packed copy in wsW)
    const float* __restrict__ bih,    // [1024]
    const float* __restrict__ bhh,    // [1024]
    const float* __restrict__ Wfc,    // [257]
    const float* __restrict__ bfc,    // [1]
    const float* __restrict__ Wfcf,   // [512]
    const float* __restrict__ bfcf,   // [1]
    const f16* __restrict__ wsW,      // [32][1024][8] packed Whh fp16
    float* __restrict__ outp)         // [512] out ++ [512][127][127] weight
{
  // tE1 row: 4 chunks of 64 elems at offsets g*68 (34 dwords -> bank shift 2/g:
  // conflict-free for the PhaseB b64 pattern; g*64 was 4-way same-bank).
  __shared__ __align__(16) f16 tE1[2][T127][272];   // 138176 B
  __shared__ __align__(16) f16 hch[2][4][136];      // [h;c] fp16, chunk stride 272 B
  __shared__ __align__(16) float s_arr[2][4][68];   // s = tanh(u+b1)
  __shared__ __align__(16) float score_s[2][128];
  __shared__ __align__(16) float p_s[2][128];       // e . Wfc[0:256]
  __shared__ __align__(16) float q_s[2][128];       // e . Wfcf[256:512]
  __shared__ __align__(16) char ovl[9216];          // est [16][288] f16 UNION gact [2][1024] f32
  __shared__ __align__(16) float c_s[2][256];       // exact fp32 cell state
  __shared__ __align__(16) float w2_lds[256];
  __shared__ __align__(16) float yh_s[2][128];
  __shared__ float ytil[2], ctxq_s[2], red[16];

  float* gact = (float*)ovl;
  f16* est = (f16*)ovl;   // est row: chunks at g*72 (36 dwords: conflict-free, 16B-aligned)

  const int L = threadIdx.x;
  const int b0 = blockIdx.x * 2;
  const int k_u = L >> 2;  // output index 0..255 (u / score-pair)
  const int g_u = L & 3;   // quad member: col-chunk selector

  // ---------------- init ----------------
  for (int i = L; i < 1088; i += 1024) ((f16*)hch)[i] = (f16)0.f;
  if (L < 512) ((float*)c_s)[L] = 0.f;
  if (L < 256) {
    w2_lds[L] = Wa2[L];
    int bb = L >> 7, tt = L & 127;
    if (tt < T127) yh_s[bb][tt] = yhist[(size_t)(b0 + bb) * T127 + tt];
  }

  // ---------------- prologue: tE1 = tanh(e.W1e), p, q ----------------
  {
    // quad-split W1e: lane holds 64 cols (32 h2 regs)
    h2 we1[32];
    {
      const float4* wrow = (const float4*)(Wa1 + (size_t)k_u * 768 + 512 + g_u * 64);
#pragma unroll
      for (int i = 0; i < 16; ++i) {
        float4 w = wrow[i];
        we1[2 * i]     = mk2((f16)w.x, (f16)w.y);
        we1[2 * i + 1] = mk2((f16)w.z, (f16)w.w);
      }
    }
    const int prpair = L >> 6;  // wave id = staging pair 0..15
    const int lm = L & 63;
    const int sg = lm >> 4;           // staging chunk 0..3
    const int si = (lm * 4) & 63;     // within-chunk elem

#pragma unroll 1
    for (int tt = 0; tt < 16; ++tt) {
      __syncthreads();
      {  // stage 16 (b,j) rows of e as fp16: pair = bb*8 + j8, j = tt*8+j8
        int bbs = prpair >> 3, j8 = prpair & 7, j = tt * 8 + j8;
        float4 v = make_float4(0.f, 0.f, 0.f, 0.f);
        if (j < T127)
          v = *(const float4*)(enc + (((size_t)(b0 + bbs)) * T127 + j) * 256 + lm * 4);
        h4 hv; hv[0] = (f16)v.x; hv[1] = (f16)v.y; hv[2] = (f16)v.z; hv[3] = (f16)v.w;
        *(h4*)(est + prpair * 288 + sg * 72 + si) = hv;
      }
      __syncthreads();
      // every quad computes all 16 pairs: 64-col partial dot + quad reduce
#pragma unroll 1
      for (int P = 0; P < 16; ++P) {
        int bbs = P >> 3, j8 = P & 7, j = tt * 8 + j8;
        const h8* ep = (const h8*)(est + P * 288 + g_u * 72);
        float a0 = 0.f, a1 = 0.f;
#pragma unroll
        for (int r = 0; r < 8; ++r) {
          h8 e8 = ep[r];
          a0 = fdot2(we1[4 * r + 0], mk2(e8[0], e8[1]), a0);
          a1 = fdot2(we1[4 * r + 1], mk2(e8[2], e8[3]), a1);
          a0 = fdot2(we1[4 * r + 2], mk2(e8[4], e8[5]), a0);
          a1 = fdot2(we1[4 * r + 3], mk2(e8[6], e8[7]), a1);
        }
        float acc = a0 + a1;
        acc += __shfl_xor(acc, 1, 64);
        acc += __shfl_xor(acc, 2, 64);
        if (g_u == 0 && j < T127)
          tE1[bbs][j][(k_u >> 6) * 68 + (k_u & 63)] = (f16)fast_tanh(acc);
      }
      {  // p, q for this wave's pair
        int P = prpair, bbs = P >> 3, j8 = P & 7, j = tt * 8 + j8;
        float4 wp4 = *(const float4*)(Wfc + lm * 4);
        float4 wq4 = *(const float4*)(Wfcf + 256 + lm * 4);
        h4 ev = *(const h4*)(est + P * 288 + sg * 72 + si);
        float pacc = (float)ev[0] * wp4.x + (float)ev[1] * wp4.y + (float)ev[2] * wp4.z + (float)ev[3] * wp4.w;
        float qacc = (float)ev[0] * wq4.x + (float)ev[1] * wq4.y + (float)ev[2] * wq4.z + (float)ev[3] * wq4.w;
#pragma unroll
        for (int s = 32; s; s >>= 1) {
          pacc += __shfl_xor(pacc, s, 64);
          qacc += __shfl_xor(qacc, s, 64);
        }
        if (lm == 0 && j < T127) { p_s[bbs][j] = pacc; q_s[bbs][j] = qacc; }
      }
    }
  }
  __syncthreads();

  // ---------------- persistent registers ----------------
  h2 w1[64];  // Wa1[k_u, g_u*128 : +128] (h|c part), fp16
  {
    const float4* wrow = (const float4*)(Wa1 + (size_t)k_u * 768 + g_u * 128);
#pragma unroll
    for (int i = 0; i < 32; ++i) {
      float4 w = wrow[i];
      w1[2 * i]     = mk2((f16)w.x, (f16)w.y);
      w1[2 * i + 1] = mk2((f16)w.z, (f16)w.w);
    }
  }
  const float b1k = ba1[k_u];
  const float wihn = Wih[L];
  const float biasn = bih[L] + bhh[L];
  const float ba2v = ba2[0];
  const float wfcy = Wfc[256];
  const float bfc0 = bfc[0];
  __syncthreads();

  // ---------------- 127 sequential steps ----------------
#pragma unroll 1
  for (int t = 0; t < T127; ++t) {
    // prefetch first Whh stream chunks (land during u-dots)
    const h8* wp = (const h8*)wsW + L;  // chunk c at wp[c*1024]
    h8 wv0 = wp[0];
    h8 wv1 = wp[1024];

    // ---- Phase A1: u = W1.[h;c] -> s=tanh(u+b1)  (register weights) ----
    float u0a = 0.f, u0b = 0.f, u1a = 0.f, u1b = 0.f;
    {
      const h8* hp = (const h8*)&hch[0][g_u][0];
#pragma unroll
      for (int r = 0; r < 16; ++r) {
        h8 a = hp[r];
        u0a = fdot2(w1[4 * r + 0], mk2(a[0], a[1]), u0a);
        u0b = fdot2(w1[4 * r + 1], mk2(a[2], a[3]), u0b);
        u0a = fdot2(w1[4 * r + 2], mk2(a[4], a[5]), u0a);
        u0b = fdot2(w1[4 * r + 3], mk2(a[6], a[7]), u0b);
      }
      hp = (const h8*)&hch[1][g_u][0];
#pragma unroll
      for (int r = 0; r < 16; ++r) {
        h8 a = hp[r];
        u1a = fdot2(w1[4 * r + 0], mk2(a[0], a[1]), u1a);
        u1b = fdot2(w1[4 * r + 1], mk2(a[2], a[3]), u1b);
        u1a = fdot2(w1[4 * r + 2], mk2(a[4], a[5]), u1a);
        u1b = fdot2(w1[4 * r + 3], mk2(a[6], a[7]), u1b);
      }
    }

    // ---- Phase A2: gh = Whh.h, Whh streamed from L2, 2-deep pipeline ----
    float gh0 = 0.f, gh1 = 0.f;
#pragma unroll 1
    for (int cb = 0; cb < 16; ++cb) {
      int cn0 = (cb < 15) ? (cb * 2 + 2) : 0;  // wrap: harmless dummy load last iter
      int cn1 = (cb < 15) ? (cb * 2 + 3) : 1;
      h8 n0 = wp[cn0 * 1024];
      h8 n1 = wp[cn1 * 1024];
      int c0 = cb * 2, c1 = cb * 2 + 1;
      h8 h00 = *(const h8*)&hch[0][c0 >> 4][(c0 & 15) * 8];
      h8 h10 = *(const h8*)&hch[1][c0 >> 4][(c0 & 15) * 8];
      gh0 = fdot2(mk2(wv0[0], wv0[1]), mk2(h00[0], h00[1]), gh0);
      gh0 = fdot2(mk2(wv0[2], wv0[3]), mk2(h00[2], h00[3]), gh0);
      gh0 = fdot2(mk2(wv0[4], wv0[5]), mk2(h00[4], h00[5]), gh0);
      gh0 = fdot2(mk2(wv0[6], wv0[7]), mk2(h00[6], h00[7]), gh0);
      gh1 = fdot2(mk2(wv0[0], wv0[1]), mk2(h10[0], h10[1]), gh1);
      gh1 = fdot2(mk2(wv0[2], wv0[3]), mk2(h10[2], h10[3]), gh1);
      gh1 = fdot2(mk2(wv0[4], wv0[5]), mk2(h10[4], h10[5]), gh1);
      gh1 = fdot2(mk2(wv0[6], wv0[7]), mk2(h10[6], h10[7]), gh1);
      h8 h01 = *(const h8*)&hch[0][c1 >> 4][(c1 & 15) * 8];
      h8 h11 = *(const h8*)&hch[1][c1 >> 4][(c1 & 15) * 8];
      gh0 = fdot2(mk2(wv1[0], wv1[1]), mk2(h01[0], h01[1]), gh0);
      gh0 = fdot2(mk2(wv1[2], wv1[3]), mk2(h01[2], h01[3]), gh0);
      gh0 = fdot2(mk2(wv1[4], wv1[5]), mk2(h01[4], h01[5]), gh0);
      gh0 = fdot2(mk2(wv1[6], wv1[7]), mk2(h01[6], h01[7]), gh0);
      gh1 = fdot2(mk2(wv1[0], wv1[1]), mk2(h11[0], h11[1]), gh1);
      gh1 = fdot2(mk2(wv1[2], wv1[3]), mk2(h11[2], h11[3]), gh1);
      gh1 = fdot2(mk2(wv1[4], wv1[5]), mk2(h11[4], h11[5]), gh1);
      gh1 = fdot2(mk2(wv1[6], wv1[7]), mk2(h11[6], h11[7]), gh1);
      wv0 = n0; wv1 = n1;
    }

    // ---- u quad-reduce + s write ----
    float u0 = u0a + u0b, u1 = u1a + u1b;
    u0 += __shfl_xor(u0, 1, 64); u0 += __shfl_xor(u0, 2, 64);
    u1 += __shfl_xor(u1, 1, 64); u1 += __shfl_xor(u1, 2, 64);
    if (g_u == 0) s_arr[0][k_u >> 6][k_u & 63] = fast_tanh(u0 + b1k);
    else if (g_u == 1) s_arr[1][k_u >> 6][k_u & 63] = fast_tanh(u1 + b1k);
    __syncthreads();

    // ---- Phase B: scores via tanh(u+E) = (s+t)/(1+st) ----
    {
      const int pr = k_u;  // pair 0..255; valid < 254
      if (pr < 254) {
        const int bb = pr & 1;
        const int j = pr >> 1;
        const h4* tp = (const h4*)&tE1[bb][j][g_u * 68];
        const float4* sp = (const float4*)&s_arr[bb][g_u][0];
        const float4* w2p = (const float4*)&w2_lds[g_u * 64];
        float acc0 = 0.f, acc1 = 0.f;
#pragma unroll
        for (int i = 0; i < 16; ++i) {
          h4 tv = tp[i];
          float4 sv = sp[i];
          float4 wv = w2p[i];
          float t0 = (float)tv[0], t1 = (float)tv[1], t2 = (float)tv[2], t3 = (float)tv[3];
          acc0 = fmaf(wv.x * (sv.x + t0), rcp_f(fmaf(sv.x, t0, 1.f)), acc0);
          acc1 = fmaf(wv.y * (sv.y + t1), rcp_f(fmaf(sv.y, t1, 1.f)), acc1);
          acc0 = fmaf(wv.z * (sv.z + t2), rcp_f(fmaf(sv.z, t2, 1.f)), acc0);
          acc1 = fmaf(wv.w * (sv.w + t3), rcp_f(fmaf(sv.w, t3, 1.f)), acc1);
        }
        float acc = acc0 + acc1;
        acc += __shfl_xor(acc, 1, 64);
        acc += __shfl_xor(acc, 2, 64);
        if (g_u == 0) score_s[bb][j] = acc + ba2v;
      }
    }
    __syncthreads();

    // ---- Phase C: softmax, attn write, context dots, y_tilde ----
    {
      const int wv = L >> 6, ln = L & 63;
      if (wv < 2) {
        const int bb = wv;
        const int batch = b0 + bb;
        float x0 = score_s[bb][ln];
        float x1 = (ln < 63) ? score_s[bb][64 + ln] : -3.4e38f;
        float m = fmaxf(x0, x1);
#pragma unroll
        for (int s = 32; s; s >>= 1) m = fmaxf(m, __shfl_xor(m, s, 64));
        float e0 = __expf(x0 - m);
        float e1 = (ln < 63) ? __expf(x1 - m) : 0.f;
        float ssum = e0 + e1;
#pragma unroll
        for (int s = 32; s; s >>= 1) ssum += __shfl_xor(ssum, s, 64);
        float rs = rcp_f(ssum);
        float a0 = e0 * rs, a1 = e1 * rs;
        float* wout = outp + 512 + ((size_t)batch * T127 + t) * T127;
        wout[ln] = a0;
        if (ln < 63) wout[64 + ln] = a1;
        float cw = a0 * p_s[bb][ln] + ((ln < 63) ? a1 * p_s[bb][64 + ln] : 0.f);
#pragma unroll
        for (int s = 32; s; s >>= 1) cw += __shfl_xor(cw, s, 64);
        if (ln == 0) ytil[bb] = cw + wfcy * yh_s[bb][t] + bfc0;
        if (t == T127 - 1) {
          float cq = a0 * q_s[bb][ln] + ((ln < 63) ? a1 * q_s[bb][64 + ln] : 0.f);
#pragma unroll
          for (int s = 32; s; s >>= 1) cq += __shfl_xor(cq, s, 64);
          if (ln == 0) ctxq_s[bb] = cq;
        }
      }
    }
    __syncthreads();

    // ---- Phase D: gates + activations ----
    {
      float g0 = gh0 + wihn * ytil[0] + biasn;
      float g1 = gh1 + wihn * ytil[1] + biasn;
      bool is_g = (L >= 512) && (L < 768);
      float a0 = is_g ? fast_tanh(g0) : fast_sig(g0);
      float a1 = is_g ? fast_tanh(g1) : fast_sig(g1);
      gact[L] = a0;
      gact[1024 + L] = a1;
    }
    __syncthreads();

    // ---- Phase E: LSTM cell update ----
    if (L < 512) {
      const int bb = L >> 8, kk = L & 255;
      float gi = gact[bb * 1024 + kk];
      float gf = gact[bb * 1024 + 256 + kk];
      float gg = gact[bb * 1024 + 512 + kk];
      float go = gact[bb * 1024 + 768 + kk];
      float cn = gf * c_s[bb][kk] + gi * gg;
      float hn = go * fast_tanh(cn);
      c_s[bb][kk] = cn;
      hch[bb][kk >> 7][kk & 127] = (f16)hn;
      hch[bb][2 + (kk >> 7)][kk & 127] = (f16)cn;
      if (t == T127 - 1) {
        float po = Wfcf[kk] * hn;
#pragma unroll
        for (int s = 32; s; s >>= 1) po += __shfl_xor(po, s, 64);
        if ((L & 63) == 0) red[L >> 6] = po;
      }
    }
    __syncthreads();
  }

  // ---------------- final: out = Wfcf[0:256].h + ctx.Wfcf[256:512] + b ----------------
  if (L < 2) {
    float o = red[L * 4] + red[L * 4 + 1] + red[L * 4 + 2] + red[L * 4 + 3] + ctxq_s[L] + bfcf[0];
    outp[b0 + L] = o;
  }
}

extern "C" void kernel_launch(void* const* d_in, const int* in_sizes, int n_in,
                              void* d_out, int out_size, void* d_ws, size_t ws_size,
                              hipStream_t stream) {
  (void)in_sizes; (void)n_in; (void)out_size; (void)ws_size;
  f16* wsW = (f16*)d_ws;  // needs 32*1024*8*2 = 512 KiB
  pack_whh<<<1024, 256, 0, stream>>>((const float*)d_in[7], wsW);
  decoder_kernel<<<256, 1024, 0, stream>>>(
      (const float*)d_in[0], (const float*)d_in[1], (const float*)d_in[2],
      (const float*)d_in[3], (const float*)d_in[4], (const float*)d_in[5],
      (const float*)d_in[6], (const float*)d_in[7], (const float*)d_in[8],
      (const float*)d_in[9], (const float*)d_in[10], (const float*)d_in[11],
      (const float*)d_in[12], (const float*)d_in[13], wsW, (float*)d_out);
}